// Round 2
// baseline (32.976 us; speedup 1.0000x reference)
//
#include <hip/hip_runtime.h>

#define SEQ 256
#define NENV 64
#define NGROUPS 12
#define GDIM 128
#define ROWS (SEQ * NENV)           // 16384
#define WAVES_PER_BLOCK 4

// Kernel 1: fold Wg (128x128) with wa = Wa[128:256] -> v[128]
// v[d] = sum_a Wg[d][a] * Wa[128 + a]   (row-contiguous per thread, float4)
__global__ void fold_wg_wa(const float* __restrict__ Wg,
                           const float* __restrict__ Wa,
                           float* __restrict__ v) {
    const int d = threadIdx.x;            // 128 threads
    const float4* row = reinterpret_cast<const float4*>(Wg + d * 128);
    const float4* wa4 = reinterpret_cast<const float4*>(Wa + 128);
    float acc = 0.0f;
#pragma unroll
    for (int a = 0; a < 32; ++a) {
        const float4 r = row[a];
        const float4 w = wa4[a];          // uniform across threads -> s_load
        acc += r.x * w.x + r.y * w.y + r.z * w.z + r.w * w.w;
    }
    v[d] = acc;
}

// Kernel 2: one 64-lane wave per (s,e) row.
// Half-local softmax: each 32-lane half owns the 6 groups {2t+half}.
__global__ __launch_bounds__(WAVES_PER_BLOCK * 64)
void group_attn(const float* __restrict__ ge,     // (ROWS, 12, 128)
                const float* __restrict__ v,      // (128)
                float* __restrict__ out_weighted, // (ROWS, 128)
                float* __restrict__ out_weights)  // (ROWS, 12)
{
    const int wave = threadIdx.x >> 6;
    const int lane = threadIdx.x & 63;
    const int row  = blockIdx.x * WAVES_PER_BLOCK + wave;

    const int half = lane >> 5;     // 0: even groups, 1: odd groups
    const int l32  = lane & 31;     // dim block: dims [l32*4, l32*4+3]

    const float* base = ge + (size_t)row * (NGROUPS * GDIM);

    // v fragment for my 4 dims (L1/L2-resident broadcast)
    const float4 vf = *reinterpret_cast<const float4*>(v + l32 * 4);

    // Load the whole 12x128 row: 6 x (64 lanes x float4) contiguous 1KiB steps.
    // Step t: lanes 0..31 hold group 2t, lanes 32..63 hold group 2t+1.
    float4 g[6];
    float  sc[6];
#pragma unroll
    for (int t = 0; t < 6; ++t) {
        g[t] = *reinterpret_cast<const float4*>(base + t * 256 + lane * 4);
    }

    // Dot with v, reduce within each 32-lane half (xor 1,2,4,8,16 never
    // crosses the half boundary). sc[t] = score of group 2t+half.
#pragma unroll
    for (int t = 0; t < 6; ++t) {
        float p = g[t].x * vf.x + g[t].y * vf.y + g[t].z * vf.z + g[t].w * vf.w;
        p += __shfl_xor(p, 1);
        p += __shfl_xor(p, 2);
        p += __shfl_xor(p, 4);
        p += __shfl_xor(p, 8);
        p += __shfl_xor(p, 16);
        sc[t] = p;
    }

    // Softmax across all 12: combine only max and exp-sum across halves.
    float mh = fmaxf(fmaxf(fmaxf(sc[0], sc[1]), fmaxf(sc[2], sc[3])),
                     fmaxf(sc[4], sc[5]));
    const float m = fmaxf(mh, __shfl_xor(mh, 32));

    float w[6];
    float sh = 0.0f;
#pragma unroll
    for (int t = 0; t < 6; ++t) {
        w[t] = __expf(sc[t] - m);
        sh += w[t];
    }
    const float s = sh + __shfl_xor(sh, 32);
    const float inv = __builtin_amdgcn_rcpf(s);
#pragma unroll
    for (int t = 0; t < 6; ++t) w[t] *= inv;

    // Weighted sum over my half's 6 groups, then combine halves (same dims
    // live in lane^32).
    float4 acc;
    acc.x = w[0] * g[0].x; acc.y = w[0] * g[0].y;
    acc.z = w[0] * g[0].z; acc.w = w[0] * g[0].w;
#pragma unroll
    for (int t = 1; t < 6; ++t) {
        acc.x += w[t] * g[t].x;
        acc.y += w[t] * g[t].y;
        acc.z += w[t] * g[t].z;
        acc.w += w[t] * g[t].w;
    }
    acc.x += __shfl_xor(acc.x, 32);
    acc.y += __shfl_xor(acc.y, 32);
    acc.z += __shfl_xor(acc.z, 32);
    acc.w += __shfl_xor(acc.w, 32);

    if (lane < 32) {
        *reinterpret_cast<float4*>(out_weighted + (size_t)row * GDIM + l32 * 4) = acc;
    }

    // Weights: lanes l32<6 of each half write group 2*l32+half.
    // Static 6-way select (no runtime register-array index -> no scratch).
    float wv = w[0];
    if (l32 == 1) wv = w[1];
    if (l32 == 2) wv = w[2];
    if (l32 == 3) wv = w[3];
    if (l32 == 4) wv = w[4];
    if (l32 == 5) wv = w[5];
    if (l32 < NGROUPS / 2) {
        out_weights[(size_t)row * NGROUPS + 2 * l32 + half] = wv;
    }
}

extern "C" void kernel_launch(void* const* d_in, const int* in_sizes, int n_in,
                              void* d_out, int out_size, void* d_ws, size_t ws_size,
                              hipStream_t stream) {
    // Inputs: 0 robot_states (unused) 1 group_embeddings 2 Wr (unused)
    // 3 br (unused) 4 Wg 5 bg (unused) 6 Wa 7 ba (unused)
    const float* ge = (const float*)d_in[1];
    const float* Wg = (const float*)d_in[4];
    const float* Wa = (const float*)d_in[6];

    float* v = (float*)d_ws;                                   // 128 floats
    float* out_weighted = (float*)d_out;                       // ROWS*128
    float* out_weights  = out_weighted + (size_t)ROWS * GDIM;  // ROWS*12

    fold_wg_wa<<<1, 128, 0, stream>>>(Wg, Wa, v);
    group_attn<<<ROWS / WAVES_PER_BLOCK, WAVES_PER_BLOCK * 64, 0, stream>>>(
        ge, v, out_weighted, out_weights);
}